// Round 15
// baseline (673.186 us; speedup 1.0000x reference)
//
#include <hip/hip_runtime.h>
#include <hip/hip_bf16.h>
#include <math.h>

typedef __hip_bfloat16 bf16;
typedef __attribute__((ext_vector_type(8))) short short8;   // 8 bf16 (4 VGPRs)
typedef __attribute__((ext_vector_type(4))) float f32x4;

constexpr int Bc   = 4;
constexpr int NPM  = 200;
constexpr int NVM  = 1500;
constexpr int Dc   = 512;
constexpr int Hc   = 8;
constexpr int DFF  = 2048;
constexpr int NLc  = 3;
constexpr int Sc   = NPM + NVM + 2;   // 1702
constexpr int Mrows = Bc * Sc;        // 6808
constexpr int DH   = Dc / Hc;         // 64
constexpr int NTOK = NPM + NVM;       // 1700 maskable tokens
constexpr int NCH  = (Sc + 63) / 64;  // 27 dense key chunks
constexpr int NQKV = 3 * Dc;          // 1536
constexpr int GMPAD = 112;            // M-blocks (64-row) padded to multiple of 8 (XCD stripes)
constexpr int NQB  = 425;             // query blocks (425*4 = 1700)
constexpr int NTR  = 3072;            // transpose blocks in pre_layer
constexpr int NLN  = Mrows / 2;       // 3404 ln blocks (2 rows each)

__device__ __forceinline__ float toF(float v) { return v; }
__device__ __forceinline__ float toF(bf16 v)  { return __bfloat162float(v); }
__device__ __forceinline__ void  stO(float* p, float v) { *p = v; }
__device__ __forceinline__ void  stO(bf16*  p, float v) { *p = __float2bfloat16(v); }

// dtype flag computed inline from first word of ln1_s (all-ones tensor):
// fp32 1.0 = 0x3F800000, bf16 pair = 0x3F803F80.
__device__ __forceinline__ int dtypeF(const void* ones) {
    return (*(const unsigned int*)ones == 0x3F803F80u) ? 1 : 0;
}

// async global->LDS 16B: lane i's data lands at lptr + i*16 (wave-uniform lptr)
__device__ __forceinline__ void gl16(const bf16* g, bf16* l) {
    __builtin_amdgcn_global_load_lds(
        (const __attribute__((address_space(1))) unsigned int*)g,
        (__attribute__((address_space(3))) unsigned int*)l, 16, 0, 0);
}

// load 8 bf16 (16B) -> 8 floats
__device__ __forceinline__ void ld8(const bf16* p, float* out) {
    uint4 u = *(const uint4*)p;
    const unsigned short* s = (const unsigned short*)&u;
    #pragma unroll
    for (int e = 0; e < 8; e++) out[e] = __uint_as_float(((unsigned)s[e]) << 16);
}

// dual-dtype scalar load; f is wave-uniform.
__device__ __forceinline__ float ldDual(const void* p, int f, size_t i) {
    if (f) return __bfloat162float(((const bf16*)p)[i]);
    return ((const float*)p)[i];
}

// ---------------------------------------------------------------- prep: embed ∥ rel-group bins
__global__ __launch_bounds__(256) void prep(
    const void* __restrict__ vm_states, const void* __restrict__ num_step,
    const void* __restrict__ pm_states,
    const void* __restrict__ pm_W, const void* __restrict__ pm_b,
    const void* __restrict__ vm_W, const void* __restrict__ vm_b,
    const int* __restrict__ rel, const unsigned char* __restrict__ pad,
    const void* __restrict__ ones, float* __restrict__ x,
    int* __restrict__ binStart, int* __restrict__ binLen, int* __restrict__ keyList)
{
    int s = blockIdx.x;
    int b = blockIdx.y;
    int tid = threadIdx.x;

    if (s == Sc) {
        // ---- build_bins for batch b
        __shared__ int cnt[NPM];
        __shared__ int cur[NPM];
        for (int i = tid; i < NPM; i += 256) cnt[i] = 0;
        __syncthreads();
        for (int i = tid; i < NTOK; i += 256) {
            int r = rel[b * NTOK + i];
            bool ok = (r >= 0 && r < NPM);
            if (i >= NPM && pad[b * NVM + (i - NPM)] != 0) ok = false;
            if (ok) atomicAdd(&cnt[r], 1);
        }
        __syncthreads();
        if (tid == 0) {
            int acc = 0;
            for (int g = 0; g < NPM; g++) {
                cur[g] = acc; binStart[b * NPM + g] = acc; binLen[b * NPM + g] = cnt[g];
                acc += cnt[g];
            }
        }
        __syncthreads();
        for (int i = tid; i < NTOK; i += 256) {
            int r = rel[b * NTOK + i];
            bool ok = (r >= 0 && r < NPM);
            if (i >= NPM && pad[b * NVM + (i - NPM)] != 0) ok = false;
            if (ok) {
                int pos = atomicAdd(&cur[r], 1);
                keyList[b * NTOK + pos] = 1 + i;
            }
        }
        return;
    }

    // ---- embed token s
    int f = dtypeF(ones);
    float* xr = x + ((size_t)b * Sc + s) * Dc;
    if (s == 0) {
        float v = ldDual(num_step, f, b);
        xr[tid] = v; xr[tid + 256] = v;
        return;
    }
    if (s == Sc - 1) {
        xr[tid] = -1.0f; xr[tid + 256] = -1.0f;
        return;
    }
    const void *st, *W, *bias;
    size_t base;
    if (s <= NPM) { st = pm_states; base = ((size_t)b * NPM + (s - 1)) * 16; W = pm_W; bias = pm_b; }
    else          { st = vm_states; base = ((size_t)b * NVM + (s - 1 - NPM)) * 16; W = vm_W; bias = vm_b; }
    __shared__ float sv[16];
    if (tid < 16) sv[tid] = ldDual(st, f, base + tid);
    __syncthreads();
    #pragma unroll
    for (int j = 0; j < 2; j++) {
        int d = tid + j * 256;
        float a = ldDual(bias, f, d);
        #pragma unroll
        for (int c = 0; c < 16; c++)
            a += sv[c] * ldDual(W, f, (size_t)c * Dc + d);
        xr[d] = a;
    }
}

// ---------------------------------------------------------------- layernorm body (2 rows/block, float4)
__device__ __forceinline__ void ln_body(
    int rp, const float* __restrict__ x, bf16* __restrict__ h,
    const void* __restrict__ sg, const void* __restrict__ bg,
    size_t goff, int f)
{
    int sub  = threadIdx.x >> 7;          // row within block (0/1)
    int row  = rp * 2 + sub;
    int t    = threadIdx.x & 127;
    int lane = threadIdx.x & 63;
    int wv   = (threadIdx.x >> 6) & 1;    // wave within row
    const float* xr = x + (size_t)row * Dc;
    float4 v = *(const float4*)(xr + t * 4);

    __shared__ float redA[2][2];
    __shared__ float redB[2][2];

    float s = v.x + v.y + v.z + v.w;
    #pragma unroll
    for (int off = 32; off > 0; off >>= 1) s += __shfl_down(s, off);
    if (lane == 0) redA[sub][wv] = s;
    __syncthreads();
    float mean = (redA[sub][0] + redA[sub][1]) * (1.0f / Dc);

    float d0 = v.x - mean, d1 = v.y - mean, d2 = v.z - mean, d3 = v.w - mean;
    float q = d0 * d0 + d1 * d1 + d2 * d2 + d3 * d3;
    #pragma unroll
    for (int off = 32; off > 0; off >>= 1) q += __shfl_down(q, off);
    if (lane == 0) redB[sub][wv] = q;
    __syncthreads();
    float var = (redB[sub][0] + redB[sub][1]) * (1.0f / Dc);
    float rstd = rsqrtf(var + 1e-5f);

    float dd[4] = {d0, d1, d2, d3};
    unsigned short r4[4];
    #pragma unroll
    for (int e = 0; e < 4; e++) {
        int d = t * 4 + e;
        bf16 o = __float2bfloat16(dd[e] * rstd * ldDual(sg, f, goff + d) + ldDual(bg, f, goff + d));
        r4[e] = *(unsigned short*)&o;
    }
    *(uint2*)&h[(size_t)row * Dc + t * 4] = *(const uint2*)r4;
}

__global__ __launch_bounds__(256) void ln_kernel(
    const float* __restrict__ x, bf16* __restrict__ h,
    const void* __restrict__ sg, const void* __restrict__ bg,
    size_t goff, const void* __restrict__ ones)
{
    ln_body(blockIdx.x, x, h, sg, bg, goff, dtypeF(ones));
}

// ---------------------------------------------------------------- pre_layer: weight transpose ∥ ln1
__global__ __launch_bounds__(256) void pre_layer(
    const void* __restrict__ Wq, size_t oq, const void* __restrict__ Wo, size_t oo,
    const void* __restrict__ W1, size_t o1, const void* __restrict__ W2, size_t o2,
    bf16* __restrict__ Tq, bf16* __restrict__ To,
    bf16* __restrict__ T1, bf16* __restrict__ T2,
    const float* __restrict__ x, bf16* __restrict__ h,
    const void* __restrict__ sg, const void* __restrict__ bg, size_t goff,
    const void* __restrict__ ones)
{
    if (blockIdx.x >= NTR) {
        ln_body(blockIdx.x - NTR, x, h, sg, bg, goff, dtypeF(ones));
        return;
    }
    int id = blockIdx.x;
    const void* in; size_t woff; bf16* out; int R, Cn, local;
    if (id < 768)       { in = Wq; woff = oq; out = Tq; R = 512;  Cn = 1536; local = id; }
    else if (id < 1024) { in = Wo; woff = oo; out = To; R = 512;  Cn = 512;  local = id - 768; }
    else if (id < 2048) { in = W1; woff = o1; out = T1; R = 512;  Cn = 2048; local = id - 1024; }
    else                { in = W2; woff = o2; out = T2; R = 2048; Cn = 512;  local = id - 2048; }
    int nbx = Cn >> 5;
    int bx = (local % nbx) * 32, by = (local / nbx) * 32;
    __shared__ float tile[32][33];
    int tx = threadIdx.x & 31, ty = threadIdx.x >> 5;
    int f = dtypeF(ones);
    #pragma unroll
    for (int i = 0; i < 32; i += 8)
        tile[ty + i][tx] = ldDual(in, f, woff + (size_t)(by + ty + i) * Cn + bx + tx);
    __syncthreads();
    #pragma unroll
    for (int i = 0; i < 32; i += 8)
        out[(size_t)(bx + ty + i) * R + by + tx] = __float2bfloat16(tile[tx][ty + i]);
}

// ---------------------------------------------------------------- MFMA GEMM (64x64 tile, templated BK, 4-bit swizzle)
// Round-trip count is the one validated lever (BK 64->128: -15us). BK=256 for
// W2 (K=2048) halves its rounds 16->8; others stay BK=128 (LDS 32KB, 5 blk/CU).
// 4-bit involution swizzle (r14, measured 0 conflicts): LDS slot chunk c of
// row r holds global chunk c^(r&15); read chunk g from slot g^(r&15). The
// 16-lane read group spans 16 distinct low-4-XOR slots = 256B -> conflict-free
// for both row strides (256B/512B, both == 0 mod 256).
// Stage instr = 1KB: BK=128 -> 4 rows x 16 chunks (rl=quad, ch=l16);
//                BK=256 -> 2 rows x 32 chunks (rl=lane>>5, ch=lane&31).
// ACT: 0 none, 1 exact gelu, 2 qkv (scale n<512 by 0.125)
// OUTMODE: 0 bf16 store via LDS-staged coalesced writeout,
//          1 resid read-add-store (full-K), 2 atomicAdd (retired)
template<int ACT, int OUTMODE, typename OT, int BK>
__global__ __launch_bounds__(256) void gemm_mfma(
    const bf16* __restrict__ A, const bf16* __restrict__ Wt,
    const void* __restrict__ biasp, size_t boff, const void* __restrict__ ones,
    OT* __restrict__ C, int M, int N, int K, int Ksplit)
{
    constexpr int CPR = BK / 8;      // 16B chunks per row (16 or 32)
    constexpr int RPI = 512 / BK;    // rows per 1KB stage-instr (4 or 2)
    constexpr int NJI = 16 / RPI;    // stage-instrs per wave per matrix (4 or 8)
    __shared__ __align__(16) bf16 smem[128 * BK];   // As 64*BK | Ws 64*BK
    bf16* As = smem;
    bf16* Ws = smem + 64 * BK;
    int tid  = threadIdx.x;
    int wave = tid >> 6, lane = tid & 63;

    // XCD stripe remap
    unsigned nXB  = gridDim.x;
    unsigned flat = blockIdx.y * nXB + blockIdx.x;
    unsigned xcd  = flat & 7;
    unsigned slot = flat >> 3;
    unsigned yb   = xcd * (gridDim.y >> 3) + slot / nXB;
    unsigned xb   = slot - (slot / nXB) * nXB;
    int bm = yb * 64, bn = xb * 64;
    if (bm >= M) return;

    int wm = (wave & 1) * 32, wn = (wave >> 1) * 32;
    int quad = lane >> 4, l16 = lane & 15;

    int kBeg = blockIdx.z * Ksplit;
    int kEnd = kBeg + Ksplit;

    f32x4 acc[2][2] = {};

    for (int k0 = kBeg; k0 < kEnd; k0 += BK) {
        #pragma unroll
        for (int j = 0; j < NJI; j++) {
            int rl = (BK == 128) ? quad : (lane >> 5);
            int ch = (BK == 128) ? l16  : (lane & 31);
            int lr2 = j * RPI + rl;
            int sc  = (ch ^ (lr2 & 15)) * 8;           // 4-bit swizzled source chunk
            int ga  = bm + wave * 16 + lr2;
            if (ga >= M) ga = M - 1;                   // clamp: rows unused in epilogue
            gl16(A + (size_t)ga * K + k0 + sc, As + wave * 16 * BK + j * 512);
            gl16(Wt + (size_t)(bn + wave * 16 + lr2) * K + k0 + sc, Ws + wave * 16 * BK + j * 512);
        }
        __syncthreads();
        #pragma unroll
        for (int ks = 0; ks < CPR / 4; ks++) {
            int sw = ((ks * 4 + quad) ^ l16) * 8;      // 4-bit swizzled read chunk
            short8 a[2], b[2];
            #pragma unroll
            for (int mi = 0; mi < 2; mi++)
                a[mi] = *(const short8*)(As + (wm + mi * 16 + l16) * BK + sw);
            #pragma unroll
            for (int nj = 0; nj < 2; nj++)
                b[nj] = *(const short8*)(Ws + (wn + nj * 16 + l16) * BK + sw);
            #pragma unroll
            for (int mi = 0; mi < 2; mi++)
                #pragma unroll
                for (int nj = 0; nj < 2; nj++)
                    acc[mi][nj] = __builtin_amdgcn_mfma_f32_16x16x32_bf16(
                        a[mi], b[nj], acc[mi][nj], 0, 0, 0);
        }
        __syncthreads();
    }

    int f = dtypeF(ones);
    bool addBias = (blockIdx.z == 0);

    if (OUTMODE == 0) {
        // stage C tile in LDS (row pad 68), then coalesced 16B/lane writeout
        bf16* Cs = smem;                       // 64 x 68 = 8.7 KB
        #pragma unroll
        for (int mi = 0; mi < 2; mi++) {
            #pragma unroll
            for (int nj = 0; nj < 2; nj++) {
                #pragma unroll
                for (int r = 0; r < 4; r++) {
                    int row = wm + mi * 16 + quad * 4 + r;
                    int col = wn + nj * 16 + l16;
                    float c = acc[mi][nj][r];
                    if (addBias) c += ldDual(biasp, f, boff + bn + col);
                    if (ACT == 1) c = 0.5f * c * (1.0f + erff(c * 0.70710678118654752f));
                    if (ACT == 2 && ((bn + col) >> 9) == 0) c *= 0.125f;
                    Cs[row * 68 + col] = __float2bfloat16(c);
                }
            }
        }
        __syncthreads();
        #pragma unroll
        for (int p = 0; p < 2; p++) {
            int row = p * 32 + (tid >> 3);
            int col = (tid & 7) * 8;
            int gm = bm + row;
            if (gm < M)
                *(uint4*)&((bf16*)C)[(size_t)gm * N + bn + col] = *(const uint4*)&Cs[row * 68 + col];
        }
    } else {
        #pragma unroll
        for (int mi = 0; mi < 2; mi++) {
            #pragma unroll
            for (int nj = 0; nj < 2; nj++) {
                #pragma unroll
                for (int r = 0; r < 4; r++) {
                    int m = bm + wm + mi * 16 + quad * 4 + r;
                    int n = bn + wn + nj * 16 + l16;
                    if (m >= M) continue;
                    float c = acc[mi][nj][r];
                    if (addBias) c += ldDual(biasp, f, boff + n);
                    if (ACT == 1) c = 0.5f * c * (1.0f + erff(c * 0.70710678118654752f));
                    if (OUTMODE == 2) {
                        atomicAdd((float*)&C[(size_t)m * N + n], c);
                    } else {
                        float c2 = c + toF(C[(size_t)m * N + n]);
                        stO(&C[(size_t)m * N + n], c2);
                    }
                }
            }
        }
    }
}

// ---------------------------------------------------------------- sparse attention
// One query's full attention (head-fused: 8 heads via 8-lane groups).
__device__ __forceinline__ void attn_one_query(
    const bf16* __restrict__ base, int s, const int* __restrict__ kl, int total,
    int lane, int b, bf16* __restrict__ o)
{
    float q8[8];
    ld8(base + (size_t)s * NQKV + lane * 8, q8);
    float od[8] = {};
    float l = 0.f;
    for (int jj = 0; jj < total; jj += 4) {
        int kk[4]; float msk4[4];
        #pragma unroll
        for (int u = 0; u < 4; u++) {
            int j = jj + u;
            bool v = (j < total);
            int k = 0;
            if (v) k = (j == 0) ? 0 : (j == 1 ? Sc - 1 : kl[j - 2]);
            kk[u] = k; msk4[u] = v ? 1.0f : 0.0f;
        }
        float k8[4][8], v8[4][8];
        #pragma unroll
        for (int u = 0; u < 4; u++) {
            const bf16* kr = base + (size_t)kk[u] * NQKV + lane * 8;
            ld8(kr + 512, k8[u]);
            ld8(kr + 1024, v8[u]);
        }
        float t[4];
        #pragma unroll
        for (int u = 0; u < 4; u++) {
            float d0 = q8[0] * k8[u][0] + q8[1] * k8[u][1] + q8[2] * k8[u][2] + q8[3] * k8[u][3];
            float d1 = q8[4] * k8[u][4] + q8[5] * k8[u][5] + q8[6] * k8[u][6] + q8[7] * k8[u][7];
            t[u] = d0 + d1;
        }
        #pragma unroll
        for (int m2 = 1; m2 <= 4; m2 <<= 1) {
            #pragma unroll
            for (int u = 0; u < 4; u++) t[u] += __shfl_xor(t[u], m2);
        }
        #pragma unroll
        for (int u = 0; u < 4; u++) {
            float p = msk4[u] * __expf(t[u]);
            l += p;
            #pragma unroll
            for (int e = 0; e < 8; e++) od[e] += p * v8[u][e];
        }
    }
    float inv = 1.0f / l;
    unsigned short r8[8];
    #pragma unroll
    for (int e = 0; e < 8; e++) {
        bf16 v = __float2bfloat16(od[e] * inv);
        r8[e] = *(unsigned short*)&v;
    }
    *(uint4*)&o[((size_t)b * Sc + s) * Dc + lane * 8] = *(uint4*)r8;
}

// Merged attention kernel, three grid-x regions:
//  [0, NQB):         keyList-ordered sparse queries (balance+locality)
//  [NQB, 2NQB):      orphan region (invalid rel / padded) — token-ordered
//  [2NQB, 2NQB+2*NCH): dense rows q={0,Sc-1} split-K partials
__global__ __launch_bounds__(256) void attn_sparse(
    const bf16* __restrict__ qkv, const int* __restrict__ rel,
    const unsigned char* __restrict__ pad,
    const int* __restrict__ binStart, const int* __restrict__ binLen,
    const int* __restrict__ keyList, bf16* __restrict__ o,
    float* __restrict__ pOd, float* __restrict__ pL)
{
    int b = blockIdx.y;
    int wave = threadIdx.x >> 6, lane = threadIdx.x & 63;
    const bf16* base = qkv + (size_t)b * Sc * NQKV;

    if (blockIdx.x < NQB) {
        int idx = blockIdx.x * 4 + wave;            // position in keyList
        int V = binStart[b * NPM + NPM - 1] + binLen[b * NPM + NPM - 1];
        if (idx >= V) return;
        int s = keyList[b * NTOK + idx];
        int r = rel[b * NTOK + s - 1];               // valid by construction
        int start = binStart[b * NPM + r], len = binLen[b * NPM + r];
        attn_one_query(base, s, keyList + b * NTOK + start, len + 2, lane, b, o);
    } else if (blockIdx.x < 2 * NQB) {
        int s = 1 + (blockIdx.x - NQB) * 4 + wave;   // 1..1700
        int i = s - 1;
        int r = rel[b * NTOK + i];
        bool inBin = (r >= 0 && r < NPM) && !(i >= NPM && pad[b * NVM + (i - NPM)] != 0);
        if (inBin) return;                            // handled by keyList region
        int start = 0, len = 0;
        if (r >= 0 && r < NPM) { start = binStart[b * NPM + r]; len = binLen[b * NPM + r]; }
        attn_one_query(base, s, keyList + b * NTOK + start, len + 2, lane, b, o);
    } else {
        // dense rows split-K partials
        int xx = blockIdx.x - 2 * NQB;
        int c = xx % NCH;
        int q2 = xx / NCH;
        int q = q2 ? (Sc - 1) : 0;
        float q8[8];
        ld8(base + (size_t)q * NQKV + lane * 8, q8);
        float od[8] = {};
        float l = 0.f;
        #pragma unroll 2
        for (int i = 0; i < 16; i++) {
            int k = c * 64 + wave * 16 + i;
            if (k >= Sc) break;
            bool masked = (k >= 1 + NPM && k <= NPM + NVM) && (pad[b * NVM + k - 1 - NPM] != 0);
            if (!masked) {
                const bf16* kr = base + (size_t)k * NQKV + lane * 8;
                float k8[8], v8[8];
                ld8(kr + 512, k8);
                ld8(kr + 1024, v8);
                float t = q8[0]*k8[0] + q8[1]*k8[1] + q8[2]*k8[2] + q8[3]*k8[3]
                        + q8[4]*k8[4] + q8[5]*k8[5] + q8[6]*k8[6] + q8[7]*k8[7];
                #pragma unroll
                for (int m2 = 1; m2 <= 4; m2 <<= 1) t += __shfl_xor(t, m2);
                float p = __expf(t);
                l += p;
                #pragma unroll
                for (int e = 0; e < 8; e++) od[e] += p * v8[e];
            }
        }
        __shared__ float ol[4][512];
        __shared__ float ls[4][8];
        #pragma unroll
        for (int e = 0; e < 8; e++) ol[wave][lane * 8 + e] = od[e];
        if ((lane & 7) == 0) ls[wave][lane >> 3] = l;
        __syncthreads();
        int slot = (b * 2 + q2) * NCH + c;
        int tid = threadIdx.x;
        #pragma unroll
        for (int rep = 0; rep < 2; rep++) {
            int d = tid + rep * 256;
            pOd[(size_t)slot * 512 + d] = ol[0][d] + ol[1][d] + ol[2][d] + ol[3][d];
        }
        if (tid < 8) pL[slot * 8 + tid] = ls[0][tid] + ls[1][tid] + ls[2][tid] + ls[3][tid];
    }
}

__global__ __launch_bounds__(512) void attn_dense_red(
    const float* __restrict__ pOd, const float* __restrict__ pL,
    bf16* __restrict__ o)
{
    int q2 = blockIdx.x;
    int b = blockIdx.y;
    int q = q2 ? (Sc - 1) : 0;
    int d = threadIdx.x;
    int base = (b * 2 + q2) * NCH;
    float od = 0.f, l = 0.f;
    int h = d >> 6;
    for (int c = 0; c < NCH; c++) {
        od += pOd[(size_t)(base + c) * 512 + d];
        l  += pL[(base + c) * 8 + h];
    }
    o[((size_t)b * Sc + q) * Dc + d] = __float2bfloat16(od / l);
}

// ---------------------------------------------------------------- output heads (4 rows/block, 1 wave each)
__global__ __launch_bounds__(256) void out_kernel(
    const float* __restrict__ x,
    const void* __restrict__ out_W, const void* __restrict__ out_b,
    const void* __restrict__ cr_W,  const void* __restrict__ cr_b,
    const void* __restrict__ ones, void* __restrict__ out)
{
    int gid = blockIdx.x * 4 + (threadIdx.x >> 6);   // b*1501 + r
    if (gid >= Bc * (NVM + 1)) return;
    int b = gid / (NVM + 1), r = gid % (NVM + 1);
    int f = dtypeF(ones);
    const float* xr;
    const void* w;
    float bias;
    size_t oidx;
    if (r < NVM) {
        xr = x + ((size_t)b * Sc + 1 + NPM + r) * Dc;
        w = out_W; bias = ldDual(out_b, f, 0);
        oidx = (size_t)b * NVM + r;
    } else {
        xr = x + ((size_t)b * Sc + Sc - 1) * Dc;
        w = cr_W; bias = ldDual(cr_b, f, 0);
        oidx = (size_t)Bc * NVM + b;
    }
    int lane = threadIdx.x & 63;
    float t = 0.0f;
    #pragma unroll
    for (int i = 0; i < 8; i++) {
        int d = lane + i * 64;
        t += xr[d] * ldDual(w, f, d);
    }
    #pragma unroll
    for (int off = 32; off > 0; off >>= 1) t += __shfl_down(t, off);
    if (lane == 0) {
        float r2 = t + bias;
        if (f) ((bf16*)out)[oidx]  = __float2bfloat16(r2);
        else   ((float*)out)[oidx] = r2;
    }
}

// ---------------------------------------------------------------- launch
extern "C" void kernel_launch(void* const* d_in, const int* in_sizes, int n_in,
                              void* d_out, int out_size, void* d_ws, size_t ws_size,
                              hipStream_t stream)
{
    const void* vm_states = d_in[0];
    const void* num_step  = d_in[1];
    const void* pm_states = d_in[2];
    const int*  rel       = (const int*)d_in[3];
    const unsigned char* pad = (const unsigned char*)d_in[4];
    const void* pm_W  = d_in[5];
    const void* pm_b  = d_in[6];
    const void* vm_W  = d_in[7];
    const void* vm_b  = d_in[8];
    const void* ln1_s = d_in[9];
    const void* ln1_b = d_in[10];
    const void* Wqkv  = d_in[11];
    const void* bqkv  = d_in[12];
    const void* Wo    = d_in[13];
    const void* bo    = d_in[14];
    const void* ln2_s = d_in[15];
    const void* ln2_b = d_in[16];
    const void* W1    = d_in[17];
    const void* b1    = d_in[18];
    const void* W2    = d_in[19];
    const void* b2    = d_in[20];
    const void* out_W = d_in[21];
    const void* out_b = d_in[22];
    const void* cr_W  = d_in[23];
    const void* cr_b  = d_in[24];

    const size_t xsz = (size_t)Mrows * Dc;      // 3,485,696
    float* x   = (float*)((char*)d_ws + 64);
    bf16*  hb  = (bf16*)(x + xsz);
    bf16*  big = hb + xsz;                 // Mrows x 2048 max (QKV uses x1536)
    bf16*  Wt  = big + (size_t)Mrows * DFF;
    bf16*  WtQ = Wt;                       // 1536x512
    bf16*  WtO = Wt + 786432;              // 512x512
    bf16*  Wt1 = Wt + 1048576;             // 2048x512
    bf16*  Wt2 = Wt + 2097152;             // 512x2048
    int*   bins = (int*)(Wt + 3145728);
    int*   binStart = bins;                // [B][NPM]
    int*   binLen   = bins + Bc * NPM;     // [B][NPM]
    int*   keyList  = bins + 2 * Bc * NPM; // [B][NTOK]
    float* pOd = (float*)(keyList + Bc * NTOK);        // [B*2*NCH][512]
    float* pL  = pOd + (size_t)Bc * 2 * NCH * 512;     // [B*2*NCH*8]

    // embed ∥ build_bins
    prep<<<dim3(Sc + 1, Bc), 256, 0, stream>>>(
        vm_states, num_step, pm_states, pm_W, pm_b, vm_W, vm_b,
        rel, pad, ln1_s, x, binStart, binLen, keyList);

    for (int l = 0; l < NLc; l++) {
        size_t oD   = (size_t)l * Dc;
        size_t oQKV = (size_t)l * Dc * 3 * Dc;
        size_t obQ  = (size_t)l * 3 * Dc;
        size_t oWo  = (size_t)l * Dc * Dc;
        size_t oW1  = (size_t)l * Dc * DFF;
        size_t ob1  = (size_t)l * DFF;
        size_t oW2  = (size_t)l * DFF * Dc;

        // weight transpose ∥ ln1
        pre_layer<<<NTR + NLN, 256, 0, stream>>>(
            Wqkv, oQKV, Wo, oWo, W1, oW1, W2, oW2,
            WtQ, WtO, Wt1, Wt2,
            x, hb, ln1_s, ln1_b, oD, ln1_s);

        gemm_mfma<2, 0, bf16, 128><<<dim3(24, GMPAD), 256, 0, stream>>>(
            hb, WtQ, bqkv, obQ, ln1_s, big, Mrows, NQKV, Dc, Dc);

        attn_sparse<<<dim3(2 * NQB + 2 * NCH, Bc), 256, 0, stream>>>(
            big, rel, pad, binStart, binLen, keyList, hb, pOd, pL);
        attn_dense_red<<<dim3(2, Bc), 512, 0, stream>>>(pOd, pL, hb);

        // Wo: full-K read-add-store into residual x (no split-K atomics)
        gemm_mfma<0, 1, float, 128><<<dim3(8, GMPAD), 256, 0, stream>>>(
            hb, WtO, bo, oD, ln1_s, x, Mrows, Dc, Dc, Dc);

        ln_kernel<<<NLN, 256, 0, stream>>>(x, hb, ln2_s, ln2_b, oD, ln1_s);

        gemm_mfma<1, 0, bf16, 128><<<dim3(32, GMPAD), 256, 0, stream>>>(
            hb, Wt1, b1, ob1, ln1_s, big, Mrows, DFF, Dc, Dc);

        // W2: full-K read-add-store, BK=256 (rounds 16->8)
        gemm_mfma<0, 1, float, 256><<<dim3(8, GMPAD), 256, 0, stream>>>(
            big, Wt2, b2, oD, ln1_s, x, Mrows, Dc, DFF, DFF);
    }

    out_kernel<<<(Bc * (NVM + 1) + 3) / 4, 256, 0, stream>>>(x, out_W, out_b, cr_W, cr_b,
                                                             ln1_s, d_out);
}

// Round 16
// 671.809 us; speedup vs baseline: 1.0021x; 1.0021x over previous
//
#include <hip/hip_runtime.h>
#include <hip/hip_bf16.h>
#include <math.h>

typedef __hip_bfloat16 bf16;
typedef __attribute__((ext_vector_type(8))) short short8;   // 8 bf16 (4 VGPRs)
typedef __attribute__((ext_vector_type(4))) float f32x4;

constexpr int Bc   = 4;
constexpr int NPM  = 200;
constexpr int NVM  = 1500;
constexpr int Dc   = 512;
constexpr int Hc   = 8;
constexpr int DFF  = 2048;
constexpr int NLc  = 3;
constexpr int Sc   = NPM + NVM + 2;   // 1702
constexpr int Mrows = Bc * Sc;        // 6808
constexpr int DH   = Dc / Hc;         // 64
constexpr int NTOK = NPM + NVM;       // 1700 maskable tokens
constexpr int NCH  = (Sc + 63) / 64;  // 27 dense key chunks
constexpr int NQKV = 3 * Dc;          // 1536
constexpr int GMPAD = 112;            // M-blocks (64-row) padded to multiple of 8 (XCD stripes)
constexpr int NQB  = 425;             // query blocks (425*4 = 1700)
constexpr int NTR  = 3072;            // transpose blocks in pre_layer
constexpr int NLN  = Mrows / 2;       // 3404 ln blocks (2 rows each)

__device__ __forceinline__ float toF(float v) { return v; }
__device__ __forceinline__ float toF(bf16 v)  { return __bfloat162float(v); }
__device__ __forceinline__ void  stO(float* p, float v) { *p = v; }
__device__ __forceinline__ void  stO(bf16*  p, float v) { *p = __float2bfloat16(v); }

// dtype flag computed inline from first word of ln1_s (all-ones tensor):
// fp32 1.0 = 0x3F800000, bf16 pair = 0x3F803F80.
__device__ __forceinline__ int dtypeF(const void* ones) {
    return (*(const unsigned int*)ones == 0x3F803F80u) ? 1 : 0;
}

// async global->LDS 16B: lane i's data lands at lptr + i*16 (wave-uniform lptr)
__device__ __forceinline__ void gl16(const bf16* g, bf16* l) {
    __builtin_amdgcn_global_load_lds(
        (const __attribute__((address_space(1))) unsigned int*)g,
        (__attribute__((address_space(3))) unsigned int*)l, 16, 0, 0);
}

// load 8 bf16 (16B) -> 8 floats
__device__ __forceinline__ void ld8(const bf16* p, float* out) {
    uint4 u = *(const uint4*)p;
    const unsigned short* s = (const unsigned short*)&u;
    #pragma unroll
    for (int e = 0; e < 8; e++) out[e] = __uint_as_float(((unsigned)s[e]) << 16);
}

// dual-dtype scalar load; f is wave-uniform.
__device__ __forceinline__ float ldDual(const void* p, int f, size_t i) {
    if (f) return __bfloat162float(((const bf16*)p)[i]);
    return ((const float*)p)[i];
}

// ---------------------------------------------------------------- prep: embed ∥ rel-group bins
__global__ __launch_bounds__(256) void prep(
    const void* __restrict__ vm_states, const void* __restrict__ num_step,
    const void* __restrict__ pm_states,
    const void* __restrict__ pm_W, const void* __restrict__ pm_b,
    const void* __restrict__ vm_W, const void* __restrict__ vm_b,
    const int* __restrict__ rel, const unsigned char* __restrict__ pad,
    const void* __restrict__ ones, float* __restrict__ x,
    int* __restrict__ binStart, int* __restrict__ binLen, int* __restrict__ keyList)
{
    int s = blockIdx.x;
    int b = blockIdx.y;
    int tid = threadIdx.x;

    if (s == Sc) {
        // ---- build_bins for batch b
        __shared__ int cnt[NPM];
        __shared__ int cur[NPM];
        for (int i = tid; i < NPM; i += 256) cnt[i] = 0;
        __syncthreads();
        for (int i = tid; i < NTOK; i += 256) {
            int r = rel[b * NTOK + i];
            bool ok = (r >= 0 && r < NPM);
            if (i >= NPM && pad[b * NVM + (i - NPM)] != 0) ok = false;
            if (ok) atomicAdd(&cnt[r], 1);
        }
        __syncthreads();
        if (tid == 0) {
            int acc = 0;
            for (int g = 0; g < NPM; g++) {
                cur[g] = acc; binStart[b * NPM + g] = acc; binLen[b * NPM + g] = cnt[g];
                acc += cnt[g];
            }
        }
        __syncthreads();
        for (int i = tid; i < NTOK; i += 256) {
            int r = rel[b * NTOK + i];
            bool ok = (r >= 0 && r < NPM);
            if (i >= NPM && pad[b * NVM + (i - NPM)] != 0) ok = false;
            if (ok) {
                int pos = atomicAdd(&cur[r], 1);
                keyList[b * NTOK + pos] = 1 + i;
            }
        }
        return;
    }

    // ---- embed token s
    int f = dtypeF(ones);
    float* xr = x + ((size_t)b * Sc + s) * Dc;
    if (s == 0) {
        float v = ldDual(num_step, f, b);
        xr[tid] = v; xr[tid + 256] = v;
        return;
    }
    if (s == Sc - 1) {
        xr[tid] = -1.0f; xr[tid + 256] = -1.0f;
        return;
    }
    const void *st, *W, *bias;
    size_t base;
    if (s <= NPM) { st = pm_states; base = ((size_t)b * NPM + (s - 1)) * 16; W = pm_W; bias = pm_b; }
    else          { st = vm_states; base = ((size_t)b * NVM + (s - 1 - NPM)) * 16; W = vm_W; bias = vm_b; }
    __shared__ float sv[16];
    if (tid < 16) sv[tid] = ldDual(st, f, base + tid);
    __syncthreads();
    #pragma unroll
    for (int j = 0; j < 2; j++) {
        int d = tid + j * 256;
        float a = ldDual(bias, f, d);
        #pragma unroll
        for (int c = 0; c < 16; c++)
            a += sv[c] * ldDual(W, f, (size_t)c * Dc + d);
        xr[d] = a;
    }
}

// ---------------------------------------------------------------- layernorm body (2 rows/block, float4)
__device__ __forceinline__ void ln_body(
    int rp, const float* __restrict__ x, bf16* __restrict__ h,
    const void* __restrict__ sg, const void* __restrict__ bg,
    size_t goff, int f)
{
    int sub  = threadIdx.x >> 7;          // row within block (0/1)
    int row  = rp * 2 + sub;
    int t    = threadIdx.x & 127;
    int lane = threadIdx.x & 63;
    int wv   = (threadIdx.x >> 6) & 1;    // wave within row
    const float* xr = x + (size_t)row * Dc;
    float4 v = *(const float4*)(xr + t * 4);

    __shared__ float redA[2][2];
    __shared__ float redB[2][2];

    float s = v.x + v.y + v.z + v.w;
    #pragma unroll
    for (int off = 32; off > 0; off >>= 1) s += __shfl_down(s, off);
    if (lane == 0) redA[sub][wv] = s;
    __syncthreads();
    float mean = (redA[sub][0] + redA[sub][1]) * (1.0f / Dc);

    float d0 = v.x - mean, d1 = v.y - mean, d2 = v.z - mean, d3 = v.w - mean;
    float q = d0 * d0 + d1 * d1 + d2 * d2 + d3 * d3;
    #pragma unroll
    for (int off = 32; off > 0; off >>= 1) q += __shfl_down(q, off);
    if (lane == 0) redB[sub][wv] = q;
    __syncthreads();
    float var = (redB[sub][0] + redB[sub][1]) * (1.0f / Dc);
    float rstd = rsqrtf(var + 1e-5f);

    float dd[4] = {d0, d1, d2, d3};
    unsigned short r4[4];
    #pragma unroll
    for (int e = 0; e < 4; e++) {
        int d = t * 4 + e;
        bf16 o = __float2bfloat16(dd[e] * rstd * ldDual(sg, f, goff + d) + ldDual(bg, f, goff + d));
        r4[e] = *(unsigned short*)&o;
    }
    *(uint2*)&h[(size_t)row * Dc + t * 4] = *(const uint2*)r4;
}

__global__ __launch_bounds__(256) void ln_kernel(
    const float* __restrict__ x, bf16* __restrict__ h,
    const void* __restrict__ sg, const void* __restrict__ bg,
    size_t goff, const void* __restrict__ ones)
{
    ln_body(blockIdx.x, x, h, sg, bg, goff, dtypeF(ones));
}

// ---------------------------------------------------------------- pre_layer: weight transpose ∥ ln1
__global__ __launch_bounds__(256) void pre_layer(
    const void* __restrict__ Wq, size_t oq, const void* __restrict__ Wo, size_t oo,
    const void* __restrict__ W1, size_t o1, const void* __restrict__ W2, size_t o2,
    bf16* __restrict__ Tq, bf16* __restrict__ To,
    bf16* __restrict__ T1, bf16* __restrict__ T2,
    const float* __restrict__ x, bf16* __restrict__ h,
    const void* __restrict__ sg, const void* __restrict__ bg, size_t goff,
    const void* __restrict__ ones)
{
    if (blockIdx.x >= NTR) {
        ln_body(blockIdx.x - NTR, x, h, sg, bg, goff, dtypeF(ones));
        return;
    }
    int id = blockIdx.x;
    const void* in; size_t woff; bf16* out; int R, Cn, local;
    if (id < 768)       { in = Wq; woff = oq; out = Tq; R = 512;  Cn = 1536; local = id; }
    else if (id < 1024) { in = Wo; woff = oo; out = To; R = 512;  Cn = 512;  local = id - 768; }
    else if (id < 2048) { in = W1; woff = o1; out = T1; R = 512;  Cn = 2048; local = id - 1024; }
    else                { in = W2; woff = o2; out = T2; R = 2048; Cn = 512;  local = id - 2048; }
    int nbx = Cn >> 5;
    int bx = (local % nbx) * 32, by = (local / nbx) * 32;
    __shared__ float tile[32][33];
    int tx = threadIdx.x & 31, ty = threadIdx.x >> 5;
    int f = dtypeF(ones);
    #pragma unroll
    for (int i = 0; i < 32; i += 8)
        tile[ty + i][tx] = ldDual(in, f, woff + (size_t)(by + ty + i) * Cn + bx + tx);
    __syncthreads();
    #pragma unroll
    for (int i = 0; i < 32; i += 8)
        out[(size_t)(bx + ty + i) * R + by + tx] = __float2bfloat16(tile[tx][ty + i]);
}

// ---------------------------------------------------------------- MFMA GEMM (64x64 tile, templated BK, 4-bit swizzle)
// Converged configuration: BK=128 for all GEMMs (r14, session best).
// BK 64->128 halved stage->drain round-trips (-15us); BK=256 traded the
// round-count saving for lost residency (r15: neutral-to-negative) — the
// round-count lever is exhausted at BK=128.
// 4-bit involution swizzle (r14, measured 0 conflicts): LDS slot chunk c of
// row r holds global chunk c^(r&15); read chunk g from slot g^(r&15).
// ACT: 0 none, 1 exact gelu, 2 qkv (scale n<512 by 0.125)
// OUTMODE: 0 bf16 store via LDS-staged coalesced writeout,
//          1 resid read-add-store (full-K), 2 atomicAdd (retired)
template<int ACT, int OUTMODE, typename OT, int BK>
__global__ __launch_bounds__(256) void gemm_mfma(
    const bf16* __restrict__ A, const bf16* __restrict__ Wt,
    const void* __restrict__ biasp, size_t boff, const void* __restrict__ ones,
    OT* __restrict__ C, int M, int N, int K, int Ksplit)
{
    constexpr int CPR = BK / 8;      // 16B chunks per row (16 or 32)
    constexpr int RPI = 512 / BK;    // rows per 1KB stage-instr (4 or 2)
    constexpr int NJI = 16 / RPI;    // stage-instrs per wave per matrix (4 or 8)
    __shared__ __align__(16) bf16 smem[128 * BK];   // As 64*BK | Ws 64*BK
    bf16* As = smem;
    bf16* Ws = smem + 64 * BK;
    int tid  = threadIdx.x;
    int wave = tid >> 6, lane = tid & 63;

    // XCD stripe remap
    unsigned nXB  = gridDim.x;
    unsigned flat = blockIdx.y * nXB + blockIdx.x;
    unsigned xcd  = flat & 7;
    unsigned slot = flat >> 3;
    unsigned yb   = xcd * (gridDim.y >> 3) + slot / nXB;
    unsigned xb   = slot - (slot / nXB) * nXB;
    int bm = yb * 64, bn = xb * 64;
    if (bm >= M) return;

    int wm = (wave & 1) * 32, wn = (wave >> 1) * 32;
    int quad = lane >> 4, l16 = lane & 15;

    int kBeg = blockIdx.z * Ksplit;
    int kEnd = kBeg + Ksplit;

    f32x4 acc[2][2] = {};

    for (int k0 = kBeg; k0 < kEnd; k0 += BK) {
        #pragma unroll
        for (int j = 0; j < NJI; j++) {
            int rl = (BK == 128) ? quad : (lane >> 5);
            int ch = (BK == 128) ? l16  : (lane & 31);
            int lr2 = j * RPI + rl;
            int sc  = (ch ^ (lr2 & 15)) * 8;           // 4-bit swizzled source chunk
            int ga  = bm + wave * 16 + lr2;
            if (ga >= M) ga = M - 1;                   // clamp: rows unused in epilogue
            gl16(A + (size_t)ga * K + k0 + sc, As + wave * 16 * BK + j * 512);
            gl16(Wt + (size_t)(bn + wave * 16 + lr2) * K + k0 + sc, Ws + wave * 16 * BK + j * 512);
        }
        __syncthreads();
        #pragma unroll
        for (int ks = 0; ks < CPR / 4; ks++) {
            int sw = ((ks * 4 + quad) ^ l16) * 8;      // 4-bit swizzled read chunk
            short8 a[2], b[2];
            #pragma unroll
            for (int mi = 0; mi < 2; mi++)
                a[mi] = *(const short8*)(As + (wm + mi * 16 + l16) * BK + sw);
            #pragma unroll
            for (int nj = 0; nj < 2; nj++)
                b[nj] = *(const short8*)(Ws + (wn + nj * 16 + l16) * BK + sw);
            #pragma unroll
            for (int mi = 0; mi < 2; mi++)
                #pragma unroll
                for (int nj = 0; nj < 2; nj++)
                    acc[mi][nj] = __builtin_amdgcn_mfma_f32_16x16x32_bf16(
                        a[mi], b[nj], acc[mi][nj], 0, 0, 0);
        }
        __syncthreads();
    }

    int f = dtypeF(ones);
    bool addBias = (blockIdx.z == 0);

    if (OUTMODE == 0) {
        // stage C tile in LDS (row pad 68), then coalesced 16B/lane writeout
        bf16* Cs = smem;                       // 64 x 68 = 8.7 KB
        #pragma unroll
        for (int mi = 0; mi < 2; mi++) {
            #pragma unroll
            for (int nj = 0; nj < 2; nj++) {
                #pragma unroll
                for (int r = 0; r < 4; r++) {
                    int row = wm + mi * 16 + quad * 4 + r;
                    int col = wn + nj * 16 + l16;
                    float c = acc[mi][nj][r];
                    if (addBias) c += ldDual(biasp, f, boff + bn + col);
                    if (ACT == 1) c = 0.5f * c * (1.0f + erff(c * 0.70710678118654752f));
                    if (ACT == 2 && ((bn + col) >> 9) == 0) c *= 0.125f;
                    Cs[row * 68 + col] = __float2bfloat16(c);
                }
            }
        }
        __syncthreads();
        #pragma unroll
        for (int p = 0; p < 2; p++) {
            int row = p * 32 + (tid >> 3);
            int col = (tid & 7) * 8;
            int gm = bm + row;
            if (gm < M)
                *(uint4*)&((bf16*)C)[(size_t)gm * N + bn + col] = *(const uint4*)&Cs[row * 68 + col];
        }
    } else {
        #pragma unroll
        for (int mi = 0; mi < 2; mi++) {
            #pragma unroll
            for (int nj = 0; nj < 2; nj++) {
                #pragma unroll
                for (int r = 0; r < 4; r++) {
                    int m = bm + wm + mi * 16 + quad * 4 + r;
                    int n = bn + wn + nj * 16 + l16;
                    if (m >= M) continue;
                    float c = acc[mi][nj][r];
                    if (addBias) c += ldDual(biasp, f, boff + n);
                    if (ACT == 1) c = 0.5f * c * (1.0f + erff(c * 0.70710678118654752f));
                    if (OUTMODE == 2) {
                        atomicAdd((float*)&C[(size_t)m * N + n], c);
                    } else {
                        float c2 = c + toF(C[(size_t)m * N + n]);
                        stO(&C[(size_t)m * N + n], c2);
                    }
                }
            }
        }
    }
}

// ---------------------------------------------------------------- sparse attention
// One query's full attention (head-fused: 8 heads via 8-lane groups).
__device__ __forceinline__ void attn_one_query(
    const bf16* __restrict__ base, int s, const int* __restrict__ kl, int total,
    int lane, int b, bf16* __restrict__ o)
{
    float q8[8];
    ld8(base + (size_t)s * NQKV + lane * 8, q8);
    float od[8] = {};
    float l = 0.f;
    for (int jj = 0; jj < total; jj += 4) {
        int kk[4]; float msk4[4];
        #pragma unroll
        for (int u = 0; u < 4; u++) {
            int j = jj + u;
            bool v = (j < total);
            int k = 0;
            if (v) k = (j == 0) ? 0 : (j == 1 ? Sc - 1 : kl[j - 2]);
            kk[u] = k; msk4[u] = v ? 1.0f : 0.0f;
        }
        float k8[4][8], v8[4][8];
        #pragma unroll
        for (int u = 0; u < 4; u++) {
            const bf16* kr = base + (size_t)kk[u] * NQKV + lane * 8;
            ld8(kr + 512, k8[u]);
            ld8(kr + 1024, v8[u]);
        }
        float t[4];
        #pragma unroll
        for (int u = 0; u < 4; u++) {
            float d0 = q8[0] * k8[u][0] + q8[1] * k8[u][1] + q8[2] * k8[u][2] + q8[3] * k8[u][3];
            float d1 = q8[4] * k8[u][4] + q8[5] * k8[u][5] + q8[6] * k8[u][6] + q8[7] * k8[u][7];
            t[u] = d0 + d1;
        }
        #pragma unroll
        for (int m2 = 1; m2 <= 4; m2 <<= 1) {
            #pragma unroll
            for (int u = 0; u < 4; u++) t[u] += __shfl_xor(t[u], m2);
        }
        #pragma unroll
        for (int u = 0; u < 4; u++) {
            float p = msk4[u] * __expf(t[u]);
            l += p;
            #pragma unroll
            for (int e = 0; e < 8; e++) od[e] += p * v8[u][e];
        }
    }
    float inv = 1.0f / l;
    unsigned short r8[8];
    #pragma unroll
    for (int e = 0; e < 8; e++) {
        bf16 v = __float2bfloat16(od[e] * inv);
        r8[e] = *(unsigned short*)&v;
    }
    *(uint4*)&o[((size_t)b * Sc + s) * Dc + lane * 8] = *(uint4*)r8;
}

// Merged attention kernel, three grid-x regions:
//  [0, NQB):         keyList-ordered sparse queries (balance+locality)
//  [NQB, 2NQB):      orphan region (invalid rel / padded) — token-ordered
//  [2NQB, 2NQB+2*NCH): dense rows q={0,Sc-1} split-K partials
__global__ __launch_bounds__(256) void attn_sparse(
    const bf16* __restrict__ qkv, const int* __restrict__ rel,
    const unsigned char* __restrict__ pad,
    const int* __restrict__ binStart, const int* __restrict__ binLen,
    const int* __restrict__ keyList, bf16* __restrict__ o,
    float* __restrict__ pOd, float* __restrict__ pL)
{
    int b = blockIdx.y;
    int wave = threadIdx.x >> 6, lane = threadIdx.x & 63;
    const bf16* base = qkv + (size_t)b * Sc * NQKV;

    if (blockIdx.x < NQB) {
        int idx = blockIdx.x * 4 + wave;            // position in keyList
        int V = binStart[b * NPM + NPM - 1] + binLen[b * NPM + NPM - 1];
        if (idx >= V) return;
        int s = keyList[b * NTOK + idx];
        int r = rel[b * NTOK + s - 1];               // valid by construction
        int start = binStart[b * NPM + r], len = binLen[b * NPM + r];
        attn_one_query(base, s, keyList + b * NTOK + start, len + 2, lane, b, o);
    } else if (blockIdx.x < 2 * NQB) {
        int s = 1 + (blockIdx.x - NQB) * 4 + wave;   // 1..1700
        int i = s - 1;
        int r = rel[b * NTOK + i];
        bool inBin = (r >= 0 && r < NPM) && !(i >= NPM && pad[b * NVM + (i - NPM)] != 0);
        if (inBin) return;                            // handled by keyList region
        int start = 0, len = 0;
        if (r >= 0 && r < NPM) { start = binStart[b * NPM + r]; len = binLen[b * NPM + r]; }
        attn_one_query(base, s, keyList + b * NTOK + start, len + 2, lane, b, o);
    } else {
        // dense rows split-K partials
        int xx = blockIdx.x - 2 * NQB;
        int c = xx % NCH;
        int q2 = xx / NCH;
        int q = q2 ? (Sc - 1) : 0;
        float q8[8];
        ld8(base + (size_t)q * NQKV + lane * 8, q8);
        float od[8] = {};
        float l = 0.f;
        #pragma unroll 2
        for (int i = 0; i < 16; i++) {
            int k = c * 64 + wave * 16 + i;
            if (k >= Sc) break;
            bool masked = (k >= 1 + NPM && k <= NPM + NVM) && (pad[b * NVM + k - 1 - NPM] != 0);
            if (!masked) {
                const bf16* kr = base + (size_t)k * NQKV + lane * 8;
                float k8[8], v8[8];
                ld8(kr + 512, k8);
                ld8(kr + 1024, v8);
                float t = q8[0]*k8[0] + q8[1]*k8[1] + q8[2]*k8[2] + q8[3]*k8[3]
                        + q8[4]*k8[4] + q8[5]*k8[5] + q8[6]*k8[6] + q8[7]*k8[7];
                #pragma unroll
                for (int m2 = 1; m2 <= 4; m2 <<= 1) t += __shfl_xor(t, m2);
                float p = __expf(t);
                l += p;
                #pragma unroll
                for (int e = 0; e < 8; e++) od[e] += p * v8[e];
            }
        }
        __shared__ float ol[4][512];
        __shared__ float ls[4][8];
        #pragma unroll
        for (int e = 0; e < 8; e++) ol[wave][lane * 8 + e] = od[e];
        if ((lane & 7) == 0) ls[wave][lane >> 3] = l;
        __syncthreads();
        int slot = (b * 2 + q2) * NCH + c;
        int tid = threadIdx.x;
        #pragma unroll
        for (int rep = 0; rep < 2; rep++) {
            int d = tid + rep * 256;
            pOd[(size_t)slot * 512 + d] = ol[0][d] + ol[1][d] + ol[2][d] + ol[3][d];
        }
        if (tid < 8) pL[slot * 8 + tid] = ls[0][tid] + ls[1][tid] + ls[2][tid] + ls[3][tid];
    }
}

__global__ __launch_bounds__(512) void attn_dense_red(
    const float* __restrict__ pOd, const float* __restrict__ pL,
    bf16* __restrict__ o)
{
    int q2 = blockIdx.x;
    int b = blockIdx.y;
    int q = q2 ? (Sc - 1) : 0;
    int d = threadIdx.x;
    int base = (b * 2 + q2) * NCH;
    float od = 0.f, l = 0.f;
    int h = d >> 6;
    for (int c = 0; c < NCH; c++) {
        od += pOd[(size_t)(base + c) * 512 + d];
        l  += pL[(base + c) * 8 + h];
    }
    o[((size_t)b * Sc + q) * Dc + d] = __float2bfloat16(od / l);
}

// ---------------------------------------------------------------- output heads (4 rows/block, 1 wave each)
__global__ __launch_bounds__(256) void out_kernel(
    const float* __restrict__ x,
    const void* __restrict__ out_W, const void* __restrict__ out_b,
    const void* __restrict__ cr_W,  const void* __restrict__ cr_b,
    const void* __restrict__ ones, void* __restrict__ out)
{
    int gid = blockIdx.x * 4 + (threadIdx.x >> 6);   // b*1501 + r
    if (gid >= Bc * (NVM + 1)) return;
    int b = gid / (NVM + 1), r = gid % (NVM + 1);
    int f = dtypeF(ones);
    const float* xr;
    const void* w;
    float bias;
    size_t oidx;
    if (r < NVM) {
        xr = x + ((size_t)b * Sc + 1 + NPM + r) * Dc;
        w = out_W; bias = ldDual(out_b, f, 0);
        oidx = (size_t)b * NVM + r;
    } else {
        xr = x + ((size_t)b * Sc + Sc - 1) * Dc;
        w = cr_W; bias = ldDual(cr_b, f, 0);
        oidx = (size_t)Bc * NVM + b;
    }
    int lane = threadIdx.x & 63;
    float t = 0.0f;
    #pragma unroll
    for (int i = 0; i < 8; i++) {
        int d = lane + i * 64;
        t += xr[d] * ldDual(w, f, d);
    }
    #pragma unroll
    for (int off = 32; off > 0; off >>= 1) t += __shfl_down(t, off);
    if (lane == 0) {
        float r2 = t + bias;
        if (f) ((bf16*)out)[oidx]  = __float2bfloat16(r2);
        else   ((float*)out)[oidx] = r2;
    }
}

// ---------------------------------------------------------------- launch
extern "C" void kernel_launch(void* const* d_in, const int* in_sizes, int n_in,
                              void* d_out, int out_size, void* d_ws, size_t ws_size,
                              hipStream_t stream)
{
    const void* vm_states = d_in[0];
    const void* num_step  = d_in[1];
    const void* pm_states = d_in[2];
    const int*  rel       = (const int*)d_in[3];
    const unsigned char* pad = (const unsigned char*)d_in[4];
    const void* pm_W  = d_in[5];
    const void* pm_b  = d_in[6];
    const void* vm_W  = d_in[7];
    const void* vm_b  = d_in[8];
    const void* ln1_s = d_in[9];
    const void* ln1_b = d_in[10];
    const void* Wqkv  = d_in[11];
    const void* bqkv  = d_in[12];
    const void* Wo    = d_in[13];
    const void* bo    = d_in[14];
    const void* ln2_s = d_in[15];
    const void* ln2_b = d_in[16];
    const void* W1    = d_in[17];
    const void* b1    = d_in[18];
    const void* W2    = d_in[19];
    const void* b2    = d_in[20];
    const void* out_W = d_in[21];
    const void* out_b = d_in[22];
    const void* cr_W  = d_in[23];
    const void* cr_b  = d_in[24];

    const size_t xsz = (size_t)Mrows * Dc;      // 3,485,696
    float* x   = (float*)((char*)d_ws + 64);
    bf16*  hb  = (bf16*)(x + xsz);
    bf16*  big = hb + xsz;                 // Mrows x 2048 max (QKV uses x1536)
    bf16*  Wt  = big + (size_t)Mrows * DFF;
    bf16*  WtQ = Wt;                       // 1536x512
    bf16*  WtO = Wt + 786432;              // 512x512
    bf16*  Wt1 = Wt + 1048576;             // 2048x512
    bf16*  Wt2 = Wt + 2097152;             // 512x2048
    int*   bins = (int*)(Wt + 3145728);
    int*   binStart = bins;                // [B][NPM]
    int*   binLen   = bins + Bc * NPM;     // [B][NPM]
    int*   keyList  = bins + 2 * Bc * NPM; // [B][NTOK]
    float* pOd = (float*)(keyList + Bc * NTOK);        // [B*2*NCH][512]
    float* pL  = pOd + (size_t)Bc * 2 * NCH * 512;     // [B*2*NCH*8]

    // embed ∥ build_bins
    prep<<<dim3(Sc + 1, Bc), 256, 0, stream>>>(
        vm_states, num_step, pm_states, pm_W, pm_b, vm_W, vm_b,
        rel, pad, ln1_s, x, binStart, binLen, keyList);

    for (int l = 0; l < NLc; l++) {
        size_t oD   = (size_t)l * Dc;
        size_t oQKV = (size_t)l * Dc * 3 * Dc;
        size_t obQ  = (size_t)l * 3 * Dc;
        size_t oWo  = (size_t)l * Dc * Dc;
        size_t oW1  = (size_t)l * Dc * DFF;
        size_t ob1  = (size_t)l * DFF;
        size_t oW2  = (size_t)l * DFF * Dc;

        // weight transpose ∥ ln1
        pre_layer<<<NTR + NLN, 256, 0, stream>>>(
            Wqkv, oQKV, Wo, oWo, W1, oW1, W2, oW2,
            WtQ, WtO, Wt1, Wt2,
            x, hb, ln1_s, ln1_b, oD, ln1_s);

        gemm_mfma<2, 0, bf16, 128><<<dim3(24, GMPAD), 256, 0, stream>>>(
            hb, WtQ, bqkv, obQ, ln1_s, big, Mrows, NQKV, Dc, Dc);

        attn_sparse<<<dim3(2 * NQB + 2 * NCH, Bc), 256, 0, stream>>>(
            big, rel, pad, binStart, binLen, keyList, hb, pOd, pL);
        attn_dense_red<<<dim3(2, Bc), 512, 0, stream>>>(pOd, pL, hb);

        // Wo: full-K read-add-store into residual x (no split-K atomics)
        gemm_mfma<0, 1, float, 128><<<dim3(8, GMPAD), 256, 0, stream>>>(
            hb, WtO, bo, oD, ln1_s, x, Mrows, Dc, Dc, Dc);

        ln_kernel<<<NLN, 256, 0, stream>>>(x, hb, ln2_s, ln2_b, oD, ln1_s);

        gemm_mfma<1, 0, bf16, 128><<<dim3(32, GMPAD), 256, 0, stream>>>(
            hb, Wt1, b1, ob1, ln1_s, big, Mrows, DFF, Dc, Dc);

        // W2: full-K read-add-store, BK=128 (r15 showed BK=256 trades rounds for residency, net negative)
        gemm_mfma<0, 1, float, 128><<<dim3(8, GMPAD), 256, 0, stream>>>(
            big, Wt2, b2, oD, ln1_s, x, Mrows, Dc, DFF, DFF);
    }

    out_kernel<<<(Bc * (NVM + 1) + 3) / 4, 256, 0, stream>>>(x, out_W, out_b, cr_W, cr_b,
                                                             ln1_s, d_out);
}